// Round 9
// baseline (806.690 us; speedup 1.0000x reference)
//
#include <hip/hip_runtime.h>

#define DEV __device__ __forceinline__

typedef __bf16 bf16x8 __attribute__((ext_vector_type(8)));
typedef float f32x4 __attribute__((ext_vector_type(4)));
typedef unsigned short u16x8 __attribute__((ext_vector_type(8)));
typedef unsigned short u16x2 __attribute__((ext_vector_type(2)));

DEV unsigned short f2bf(float f) {
  unsigned int u = __float_as_uint(f);
  u += 0x7fffu + ((u >> 16) & 1u);   // RNE
  return (unsigned short)(u >> 16);
}
DEV float bf2f(unsigned short h) {
  return __uint_as_float(((unsigned int)h) << 16);
}
DEV void gload16(const void* g, void* l) {
  __builtin_amdgcn_global_load_lds(
      (const __attribute__((address_space(1))) unsigned int*)g,
      (__attribute__((address_space(3))) unsigned int*)l, 16, 0, 0);
}
DEV f32x4 mfma16(bf16x8 a, bf16x8 b, f32x4 c) {
  return __builtin_amdgcn_mfma_f32_16x16x32_bf16(a, b, c, 0, 0, 0);
}

#define SB    __builtin_amdgcn_s_barrier()
#define SCH   __builtin_amdgcn_sched_barrier(0)
#define LGKM0 asm volatile("s_waitcnt lgkmcnt(0)" ::: "memory")
#define LGKM8 asm volatile("s_waitcnt lgkmcnt(8)" ::: "memory")
#define VM4   asm volatile("s_waitcnt vmcnt(4)" ::: "memory")
#define PRIO1 __builtin_amdgcn_s_setprio(1)
#define PRIO0 __builtin_amdgcn_s_setprio(0)

// ---------------- fp32 -> bf16 convert (weights) ----------------
__global__ __launch_bounds__(256) void k_cvt(const float* __restrict__ in,
                                             unsigned short* __restrict__ out, int n8) {
  const int stride = gridDim.x * 256;
  for (int i = blockIdx.x * 256 + threadIdx.x; i < n8; i += stride) {
    const float4* p = (const float4*)(in + (long)i * 8);
    const float4 a = p[0], b = p[1];
    u16x8 o = { f2bf(a.x), f2bf(a.y), f2bf(a.z), f2bf(a.w),
                f2bf(b.x), f2bf(b.y), f2bf(b.z), f2bf(b.w) };
    *(u16x8*)(out + (long)i * 8) = o;
  }
}

// ---------------- out += partial (fp32, float4) ----------------
__global__ __launch_bounds__(256) void k_add(float* __restrict__ out,
                                             const float* __restrict__ p, int n4) {
  const int stride = gridDim.x * 256;
  for (int i = blockIdx.x * 256 + threadIdx.x; i < n4; i += stride) {
    float4 a = ((const float4*)out)[i];
    const float4 b = ((const float4*)p)[i];
    a.x += b.x; a.y += b.y; a.z += b.z; a.w += b.w;
    ((float4*)out)[i] = a;
  }
}

// ---------------- RMSNorm: fp32 [rows,2048] -> bf16 ----------------
__global__ __launch_bounds__(256) void k_rmsnorm(const float* __restrict__ x,
                                                 const float* __restrict__ g,
                                                 unsigned short* __restrict__ out) {
  const int row = blockIdx.x;
  const int t = threadIdx.x;
  const float4* xr = (const float4*)(x + (long)row * 2048);
  const float4 a = xr[t * 2], c = xr[t * 2 + 1];
  float ss = a.x * a.x + a.y * a.y + a.z * a.z + a.w * a.w +
             c.x * c.x + c.y * c.y + c.z * c.z + c.w * c.w;
#pragma unroll
  for (int o = 32; o > 0; o >>= 1) ss += __shfl_down(ss, o);
  __shared__ float ws4[4];
  __shared__ float invs;
  if ((t & 63) == 0) ws4[t >> 6] = ss;
  __syncthreads();
  if (t == 0) invs = 1.0f / sqrtf((ws4[0] + ws4[1] + ws4[2] + ws4[3]) * (1.0f / 2048.0f) + 1e-5f);
  __syncthreads();
  const float inv = invs;
  const float4* gr = (const float4*)g;
  const float4 g0 = gr[t * 2], g1v = gr[t * 2 + 1];
  u16x8 o8 = { f2bf(a.x * inv * g0.x),  f2bf(a.y * inv * g0.y),
               f2bf(a.z * inv * g0.z),  f2bf(a.w * inv * g0.w),
               f2bf(c.x * inv * g1v.x), f2bf(c.y * inv * g1v.y),
               f2bf(c.z * inv * g1v.z), f2bf(c.w * inv * g1v.w) };
  *(u16x8*)(out + (long)row * 2048 + t * 8) = o8;
}

// ======== 256x256 GEMM — faithful 8-phase/2-K-tile template (m201 port) ====
// Static LDS buffer indices (unrolled 2 tiles/iter); 1 half-tile staged per phase:
//   P1:A0(u+1)->b1  P2:A1(u+1)->b1  P3:B0(u+2)->b0  P4:B1(u+2)->b0  [vmcnt(4)]
//   P5:A0(u+2)->b0  P6:A1(u+2)->b0  P7:B0(u+3)->b1  P8:B1(u+3)->b1  [vmcnt(4)]
// Each phase: reads; stage; [lgkm(8) if 12 reads]; SB; lgkm(0); 16 MFMA; SB.
// EPI 0: bf16. 1: outF=resid+acc. 2: outBF=silu(aux)*acc. 3: split-K2.
template <int EPI>
__global__ __launch_bounds__(512, 2) void k_gemm256(
    const unsigned short* __restrict__ A, const unsigned short* __restrict__ B,
    unsigned short* __restrict__ outBF, float* __restrict__ outF,
    const float* __restrict__ resid, const unsigned short* __restrict__ aux,
    float* __restrict__ partial, int M, int N, int K, int Keff) {
  __shared__ __align__(16) unsigned short lds[2][2][2][128][64];
  const int tid = threadIdx.x;
  const int wid = tid >> 6, lane = tid & 63;
  const int wr = wid >> 2, wc = wid & 3;
  const int fr = lane & 15, g4 = lane >> 4;

  const int nwg = gridDim.x;
  int bid = blockIdx.x;
  { int q = nwg >> 3, r = nwg & 7, xcd = bid & 7, lo = bid >> 3;
    bid = (xcd < r ? xcd * (q + 1) : r * (q + 1) + (xcd - r) * q) + lo; }
  int tile = bid, ks = 0;
  if constexpr (EPI == 3) { ks = bid & 1; tile = bid >> 1; }
  const int nxb = N >> 8;
  const int bx = tile % nxb, by = tile / nxb;
  const int arow0 = by << 8, bcol0 = bx << 8;
  const int NT = Keff >> 6;
  const int NPAIR = NT >> 1;

  const int srow = tid >> 3;
  const int sg = (tid & 7) ^ (srow & 7);
  const unsigned short* Asrc = A + (long)(arow0 + srow) * K + (long)ks * Keff + (sg << 3);
  const unsigned short* Bsrc = B + (long)(bcol0 + srow) * K + (long)ks * Keff + (sg << 3);

  const int posk0 = (g4 ^ (lane & 7)) << 3;
  const int posk1 = ((4 + g4) ^ (lane & 7)) << 3;

  f32x4 acc[8][4] = {};
  bf16x8 a[4][2], b0[2][2], b1[2][2];

#define STAGE(SRC, xs, bufi, mat, h)                                            \
  { const unsigned short* s_ = (SRC) + (long)(h) * 128 * K + (long)(xs) * 64;   \
    unsigned short* d_ = &lds[bufi][mat][h][0][0] + wid * 512;                  \
    gload16(s_, d_);                                                            \
    gload16(s_ + (long)64 * K, d_ + 4096); }
#define RD_A(bufi, mh)                                                          \
  { const unsigned short* pA_ = &lds[bufi][0][wr][0][0];                        \
    _Pragma("unroll") for (int m_ = 0; m_ < 4; ++m_) {                          \
      const unsigned short* p_ = pA_ + ((mh) * 64 + m_ * 16 + fr) * 64;         \
      a[m_][0] = *(const bf16x8*)(p_ + posk0);                                  \
      a[m_][1] = *(const bf16x8*)(p_ + posk1); } }
#define RD_B(bufi, arr, nh)                                                     \
  { const unsigned short* pB_ = &lds[bufi][1][wc >> 1][0][0] + (wc & 1) * 4096; \
    _Pragma("unroll") for (int n_ = 0; n_ < 2; ++n_) {                          \
      const unsigned short* p_ = pB_ + ((nh) * 32 + n_ * 16 + fr) * 64;         \
      arr[n_][0] = *(const bf16x8*)(p_ + posk0);                                \
      arr[n_][1] = *(const bf16x8*)(p_ + posk1); } }
#define MMQ(mh, nh, Bv)                                                         \
  _Pragma("unroll") for (int k_ = 0; k_ < 2; ++k_)                              \
  _Pragma("unroll") for (int m_ = 0; m_ < 4; ++m_)                              \
  _Pragma("unroll") for (int n_ = 0; n_ < 2; ++n_)                              \
    acc[(mh)*4+m_][(nh)*2+n_] = mfma16(a[m_][k_], Bv[n_][k_], acc[(mh)*4+m_][(nh)*2+n_]);

  // prologue: tile0 (4 halves -> buf0) + B0,B1(tile1 -> buf1); vmcnt(4) retires tile0.
  STAGE(Asrc, 0, 0, 0, 0);
  STAGE(Asrc, 0, 0, 0, 1);
  STAGE(Bsrc, 0, 0, 1, 0);
  STAGE(Bsrc, 0, 0, 1, 1);
  { const int t1 = (NT > 1) ? 1 : 0;
    STAGE(Bsrc, t1, 1, 1, 0);
    STAGE(Bsrc, t1, 1, 1, 1); }
  VM4; SCH; SB;

  for (int j = 0; j < NPAIR; ++j) {
    const int u = j << 1;
    const int c1 = u + 1;
    const int c2 = (u + 2 < NT) ? u + 2 : NT - 1;
    const int c3 = (u + 3 < NT) ? u + 3 : NT - 1;

    // ---- K-tile u (buf0) ----
    RD_A(0, 0); RD_B(0, b0, 0);
    STAGE(Asrc, c1, 1, 0, 0);          // A0(u+1) -> buf1
    LGKM8; SB; LGKM0; SCH;
    PRIO1; MMQ(0, 0, b0); PRIO0; SB;

    RD_B(0, b1, 1);
    STAGE(Asrc, c1, 1, 0, 1);          // A1(u+1) -> buf1
    SB; LGKM0; SCH;
    PRIO1; MMQ(0, 1, b1); PRIO0; SB;

    RD_A(0, 1);
    STAGE(Bsrc, c2, 0, 1, 0);          // B0(u+2) -> buf0
    SB; LGKM0; SCH;
    PRIO1; MMQ(1, 1, b1); PRIO0; SB;

    STAGE(Bsrc, c2, 0, 1, 1);          // B1(u+2) -> buf0
    SB;
    PRIO1; MMQ(1, 0, b0); PRIO0;
    VM4; SCH; SB;                      // retires A0,A1(u+1): buf1 complete

    // ---- K-tile u+1 (buf1) ----
    RD_A(1, 0); RD_B(1, b0, 0);
    STAGE(Asrc, c2, 0, 0, 0);          // A0(u+2) -> buf0
    LGKM8; SB; LGKM0; SCH;
    PRIO1; MMQ(0, 0, b0); PRIO0; SB;

    RD_B(1, b1, 1);
    STAGE(Asrc, c2, 0, 0, 1);          // A1(u+2) -> buf0
    SB; LGKM0; SCH;
    PRIO1; MMQ(0, 1, b1); PRIO0; SB;

    RD_A(1, 1);
    STAGE(Bsrc, c3, 1, 1, 0);          // B0(u+3) -> buf1
    SB; LGKM0; SCH;
    PRIO1; MMQ(1, 1, b1); PRIO0; SB;

    STAGE(Bsrc, c3, 1, 1, 1);          // B1(u+3) -> buf1
    SB;
    PRIO1; MMQ(1, 0, b0); PRIO0;
    VM4; SCH; SB;                      // retires tile u+2: buf0 complete
  }
#undef STAGE
#undef RD_A
#undef RD_B
#undef MMQ

  const int er = g4 << 2;
#pragma unroll
  for (int m = 0; m < 8; ++m) {
#pragma unroll
    for (int n = 0; n < 4; ++n) {
      const int grow = arow0 + wr * 128 + m * 16 + er;
      const int gcol = bcol0 + wc * 64 + n * 16 + fr;
#pragma unroll
      for (int r = 0; r < 4; ++r) {
        const long idx = (long)(grow + r) * N + gcol;
        const float v = acc[m][n][r];
        if constexpr (EPI == 0) {
          outBF[idx] = f2bf(v);
        } else if constexpr (EPI == 1) {
          outF[idx] = resid[idx] + v;
        } else if constexpr (EPI == 2) {
          const float x1v = bf2f(aux[idx]);
          const float sl = x1v / (1.0f + __expf(-x1v));
          outBF[idx] = f2bf(sl * v);
        } else {
          if (ks == 0) outF[idx] = resid[idx] + v;
          else         partial[idx] = v;
        }
      }
    }
  }
}

// ---------------- RoPE + head split ----------------
__global__ __launch_bounds__(256) void k_rope(const unsigned short* __restrict__ qkv,
                                              const int* __restrict__ tp,
                                              unsigned short* __restrict__ Qh,
                                              unsigned short* __restrict__ Kh, int S) {
  const int row = blockIdx.x;
  const int b = row / S, s = row - b * S;
  const float pos = (float)tp[row];
  for (int p = threadIdx.x; p < 1024; p += 256) {
    const int h = p >> 6, j = p & 63;
    const float ang = pos * __expf((float)j * -0.14391156831212787f);
    const float cc = cosf(ang), sn = sinf(ang);
    const long ib = (long)row * 6144 + h * 128 + (j << 1);
    const float q1 = bf2f(qkv[ib]), q2 = bf2f(qkv[ib + 1]);
    const float k1 = bf2f(qkv[ib + 2048]), k2v = bf2f(qkv[ib + 2049]);
    const long ob = (((long)(b * 16 + h)) * S + s) * 128 + (j << 1);
    u16x2 qo = { f2bf(q1 * cc - q2 * sn), f2bf(q2 * cc + q1 * sn) };
    u16x2 ko = { f2bf(k1 * cc - k2v * sn), f2bf(k2v * cc + k1 * sn) };
    *(u16x2*)&Qh[ob] = qo;
    *(u16x2*)&Kh[ob] = ko;
  }
}

// ---------------- V transpose ----------------
__global__ __launch_bounds__(256) void k_vtrans(const unsigned short* __restrict__ qkv,
                                                unsigned short* __restrict__ Vt, int S) {
  __shared__ __align__(16) unsigned short t[128 * 72];
  const int bh = blockIdx.x, b = bh >> 4, h = bh & 15;
  const int s0 = blockIdx.y << 6;
  const int tid = threadIdx.x;
#pragma unroll
  for (int it = 0; it < 4; ++it) {
    const int sl = it * 16 + (tid >> 4);
    const int c = tid & 15;
    u16x8 v = *(const u16x8*)(qkv + ((long)(b * S + s0 + sl)) * 6144 + 4096 + h * 128 + (c << 3));
#pragma unroll
    for (int jj = 0; jj < 8; ++jj) t[(c * 8 + jj) * 72 + sl] = v[jj];
  }
  __syncthreads();
  const int d = tid >> 1, half = tid & 1;
  unsigned short* dst = Vt + ((long)bh * 128 + d) * S + s0 + half * 32;
  const unsigned short* srcr = &t[d * 72 + half * 32];
#pragma unroll
  for (int u = 0; u < 4; ++u)
    *(u16x8*)(dst + u * 8) = *(const u16x8*)(srcr + u * 8);
}

// ---------------- causal flash attention ----------------
__global__ __launch_bounds__(256) void k_attn(const unsigned short* __restrict__ Q,
                                              const unsigned short* __restrict__ Kh,
                                              const unsigned short* __restrict__ Vt,
                                              unsigned short* __restrict__ O, int S) {
  __shared__ __align__(16) unsigned short lds_k[64 * 128];
  __shared__ __align__(16) unsigned short lds_v[128 * 64];
  __shared__ __align__(16) unsigned short lds_p[4 * 16 * 64];
  const int bh = blockIdx.x;
  const int b = bh >> 4, h = bh & 15;
  const int qt = gridDim.y - 1 - blockIdx.y;
  const int q0 = qt << 6;
  const int tid = threadIdx.x, w = tid >> 6, lane = tid & 63;
  const int fr = lane & 15, g4 = lane >> 4;

  bf16x8 qf[4];
  {
    const unsigned short* qb = Q + ((long)bh * S + q0 + w * 16 + fr) * 128 + (g4 << 3);
#pragma unroll
    for (int kk = 0; kk < 4; ++kk) qf[kk] = *(const bf16x8*)(qb + kk * 32);
  }

  f32x4 accO[8] = {};
  float mrow[4], lrow[4];
#pragma unroll
  for (int r = 0; r < 4; ++r) { mrow[r] = -1e30f; lrow[r] = 0.f; }

  const int k_row = (w << 4) + g4;
  const int k_cb = fr << 4;
  const int v_row = (w << 5) + (lane >> 3);
  const int v_cb = (lane & 7) << 4;
  const long kbase = (long)bh * S * 128;
  const long vbase = (long)bh * 128 * S;

  const int ntile = qt + 1;
  for (int it = 0; it < ntile; ++it) {
    const int kv0 = it << 6;
#pragma unroll
    for (int j = 0; j < 4; ++j) {
      const int kr = k_row + j * 4;
      const int kc = k_cb ^ ((kr & 7) << 4);
      gload16(Kh + kbase + (long)(kv0 + kr) * 128 + (kc >> 1), &lds_k[w * 2048 + j * 512]);
      const int vr = v_row + j * 8;
      const int vc = v_cb ^ ((vr & 7) << 4);
      gload16(Vt + vbase + (long)vr * S + kv0 + (vc >> 1), &lds_v[w * 2048 + j * 512]);
    }
    __syncthreads();

    f32x4 sc[4] = {};
#pragma unroll
    for (int kk = 0; kk < 4; ++kk) {
      const int kb = (kk << 6) + (g4 << 4);
#pragma unroll
      for (int n = 0; n < 4; ++n) {
        const int krw = n * 16 + fr;
        const int swz = (krw & 7) << 4;
        bf16x8 kf = *(const bf16x8*)&lds_k[krw * 128 + ((kb ^ swz) >> 1)];
        sc[n] = mfma16(qf[kk], kf, sc[n]);
      }
    }

    const float scl = 0.08838834764831845f;
    float sv[4][4];
    const bool needmask = (kv0 + 63 > q0 + w * 16);
#pragma unroll
    for (int n = 0; n < 4; ++n)
#pragma unroll
      for (int r = 0; r < 4; ++r) {
        float v = sc[n][r] * scl;
        if (needmask) {
          const int qi = q0 + w * 16 + (g4 << 2) + r;
          const int ki = kv0 + n * 16 + fr;
          if (ki > qi) v = -1e30f;
        }
        sv[n][r] = v;
      }
    float corr[4];
#pragma unroll
    for (int r = 0; r < 4; ++r) {
      float tm = fmaxf(fmaxf(sv[0][r], sv[1][r]), fmaxf(sv[2][r], sv[3][r]));
      tm = fmaxf(tm, __shfl_xor(tm, 1));
      tm = fmaxf(tm, __shfl_xor(tm, 2));
      tm = fmaxf(tm, __shfl_xor(tm, 4));
      tm = fmaxf(tm, __shfl_xor(tm, 8));
      const float mn = fmaxf(mrow[r], tm);
      corr[r] = __expf(mrow[r] - mn);
      mrow[r] = mn;
    }
    float rs[4] = {0.f, 0.f, 0.f, 0.f};
#pragma unroll
    for (int n = 0; n < 4; ++n)
#pragma unroll
      for (int r = 0; r < 4; ++r) {
        const float p = __expf(sv[n][r] - mrow[r]);
        rs[r] += p;
        const int pr = (g4 << 2) + r;
        const int pc = (n * 16 + fr) << 1;
        lds_p[(w << 10) + pr * 64 + ((pc ^ ((pr & 7) << 4)) >> 1)] = f2bf(p);
      }
#pragma unroll
    for (int r = 0; r < 4; ++r) {
      float s = rs[r];
      s += __shfl_xor(s, 1);
      s += __shfl_xor(s, 2);
      s += __shfl_xor(s, 4);
      s += __shfl_xor(s, 8);
      lrow[r] = lrow[r] * corr[r] + s;
    }
#pragma unroll
    for (int cb = 0; cb < 8; ++cb)
#pragma unroll
      for (int r = 0; r < 4; ++r) accO[cb][r] *= corr[r];

#pragma unroll
    for (int kk = 0; kk < 2; ++kk) {
      const int pb = (kk << 6) + (g4 << 4);
      bf16x8 pf = *(const bf16x8*)&lds_p[(w << 10) + fr * 64 + ((pb ^ ((fr & 7) << 4)) >> 1)];
#pragma unroll
      for (int cb = 0; cb < 8; ++cb) {
        const int vrw = cb * 16 + fr;
        bf16x8 vf = *(const bf16x8*)&lds_v[vrw * 64 + ((pb ^ ((vrw & 7) << 4)) >> 1)];
        accO[cb] = mfma16(pf, vf, accO[cb]);
      }
    }
    __syncthreads();
  }

#pragma unroll
  for (int cb = 0; cb < 8; ++cb)
#pragma unroll
    for (int r = 0; r < 4; ++r) {
      const int si = q0 + w * 16 + (g4 << 2) + r;
      const float o = accO[cb][r] / lrow[r];
      O[((long)b * S + si) * 2048 + h * 128 + cb * 16 + fr] = f2bf(o);
    }
}

// ---------------- launch ----------------
// Workspace overlay (176 MB), liveness by stream order:
//  [0,64): Qh/Kh/Vt/O -> t_bf | [64,112): qkv -> x2+... | [96,112): wo -> h2
//  [112,144): wqkv -> w1 -> w2 | [144,176): h1 -> partWo -> w3 -> partW2
extern "C" void kernel_launch(void* const* d_in, const int* in_sizes, int n_in,
                              void* d_out, int out_size, void* d_ws, size_t ws_size,
                              hipStream_t stream) {
  const float* x    = (const float*)d_in[0];
  const int*   tp   = (const int*)d_in[1];
  const float* Wqkv = (const float*)d_in[2];
  const float* Wo   = (const float*)d_in[3];
  const float* g1   = (const float*)d_in[4];
  const float* g2   = (const float*)d_in[5];
  const float* W1   = (const float*)d_in[6];
  const float* W3   = (const float*)d_in[7];
  const float* W2   = (const float*)d_in[8];
  float* out = (float*)d_out;

  char* ws = (char*)d_ws;
  const size_t MB = 1024 * 1024;
  unsigned short* Qh      = (unsigned short*)(ws + 0 * MB);
  unsigned short* Kh      = (unsigned short*)(ws + 16 * MB);
  unsigned short* Vt      = (unsigned short*)(ws + 32 * MB);
  unsigned short* O_bf    = (unsigned short*)(ws + 48 * MB);
  unsigned short* t_bf    = (unsigned short*)(ws + 0 * MB);
  unsigned short* qkv_bf  = (unsigned short*)(ws + 64 * MB);
  float*          x2      = (float*)         (ws + 64 * MB);
  unsigned short* h2_bf   = (unsigned short*)(ws + 96 * MB);
  unsigned short* wo_bf   = (unsigned short*)(ws + 96 * MB);
  unsigned short* wqkv_bf = (unsigned short*)(ws + 112 * MB);
  unsigned short* w1_bf   = (unsigned short*)(ws + 112 * MB);
  unsigned short* w2_bf   = (unsigned short*)(ws + 112 * MB);
  unsigned short* h1_bf   = (unsigned short*)(ws + 144 * MB);
  float*          part    = (float*)         (ws + 144 * MB);
  unsigned short* w3_bf   = (unsigned short*)(ws + 144 * MB);

  const int S = 2048;

  // --- attention sublayer ---
  k_cvt<<<1024, 256, 0, stream>>>(Wqkv, wqkv_bf, 12582912 / 8);
  k_rmsnorm<<<4096, 256, 0, stream>>>(x, g1, h1_bf);
  k_gemm256<0><<<dim3(384), 512, 0, stream>>>(h1_bf, wqkv_bf, qkv_bf, nullptr, nullptr, nullptr, nullptr, 4096, 6144, 2048, 2048);
  k_rope<<<4096, 256, 0, stream>>>(qkv_bf, tp, Qh, Kh, S);
  k_vtrans<<<dim3(32, 32), 256, 0, stream>>>(qkv_bf, Vt, S);
  k_cvt<<<1024, 256, 0, stream>>>(Wo, wo_bf, 4194304 / 8);       // after vtrans (qkv dead)
  k_cvt<<<1024, 256, 0, stream>>>(W1, w1_bf, 16777216 / 8);      // wqkv dead
  k_attn<<<dim3(32, 32), 256, 0, stream>>>(Qh, Kh, Vt, O_bf, S);
  // Wo split-K2: 128 tiles x 2 = 256 blocks; partial at [144,176) (h1 dead)
  k_gemm256<3><<<dim3(256), 512, 0, stream>>>(O_bf, wo_bf, nullptr, x2, x, nullptr, part, 4096, 2048, 2048, 1024);
  k_add<<<2048, 256, 0, stream>>>(x2, part, 2097152);

  // --- FFN sublayer ---
  k_rmsnorm<<<4096, 256, 0, stream>>>(x2, g2, h2_bf);            // wo dead
  k_cvt<<<1024, 256, 0, stream>>>(W3, w3_bf, 16777216 / 8);      // partWo dead
  k_gemm256<0><<<dim3(512), 512, 0, stream>>>(h2_bf, w1_bf, t_bf, nullptr, nullptr, nullptr, nullptr, 4096, 8192, 2048, 2048);  // Qh..O dead
  k_cvt<<<1024, 256, 0, stream>>>(W2, w2_bf, 16777216 / 8);      // w1 dead
  k_gemm256<2><<<dim3(512), 512, 0, stream>>>(h2_bf, w3_bf, t_bf, nullptr, nullptr, t_bf, nullptr, 4096, 8192, 2048, 2048);
  // W2 split-K2: partial reuses [144,176) (w3 dead after W3 gemm)
  k_gemm256<3><<<dim3(256), 512, 0, stream>>>(t_bf, w2_bf, nullptr, out, x2, nullptr, part, 4096, 2048, 8192, 4096);
  k_add<<<2048, 256, 0, stream>>>(out, part, 2097152);
}